// Round 12
// baseline (136.851 us; speedup 1.0000x reference)
//
#include <hip/hip_runtime.h>
#include <math.h>

typedef short bf16x8 __attribute__((ext_vector_type(8)));
typedef float f32x4  __attribute__((ext_vector_type(4)));

#define N_SMPS 16384
#define N_FCNS 2048
#define D_IN 32
#define D_OUT 32
#define KNN 4
#define SPLITS 4
#define CPS 512            // centers per split
#define TILES 32           // CPS / 16
#define POOL 48            // 8 subsets x top-6, all-distinct candidates

__device__ __forceinline__ unsigned umin_u(unsigned a, unsigned b) { return a < b ? a : b; }
__device__ __forceinline__ unsigned umax_u(unsigned a, unsigned b) { return a > b ? a : b; }

// round-to-nearest-even fp32 -> bf16
__device__ __forceinline__ unsigned short bf16_rne(float f) {
  unsigned b = __float_as_uint(f);
  unsigned r = b + 0x7FFFu + ((b >> 16) & 1u);
  return (unsigned short)(r >> 16);
}

// ---------------- ws layout (bytes) ------------------------------------------
// wb 4MB | pool 3MB
#define OFF_WB   0u
#define OFF_POOL 4194304u

#define NW4 (N_FCNS * D_IN * D_OUT / 4)    // 524288 float4

// ---------------- Kernel 1: fused prep + MFMA topk ---------------------------
// Grid 1024 = 256 sample-groups x 4 splits; block = 4 waves, wave w covers 16
// samples (sbase = sg*64 + w*16) vs THIS block's split (512 ctrs, 32 tiles).
// Phase A: convert this block's flat W slice (512 float4) -> wb.
// Phase B: split half-norms -> LDS (bit-identical formula to R11 prep).
// Phase C: tile loop -- load fp32 ctr row chunk, RNE->bf16 inline, 1 MFMA,
//          packed-key top-4 ladder (identical key construction to R11).
// Phase D: per-wave subset top-6 (col-halves) -> pool (R11-compatible layout).
// fp64 deliberately absent (register budget -- the R10 spill lesson).
__global__ __launch_bounds__(256) void k_topk(
    const float* __restrict__ x, const float* __restrict__ ctrs,
    const float* __restrict__ wts, unsigned short* __restrict__ wb,
    unsigned* __restrict__ pool)
{
  __shared__ float    s_hb[CPS];                   // 2 KB
  __shared__ unsigned s_cand[4][16][16][4];        // 16 KB [wave][row][col][e]

  const int tid = threadIdx.x;
  const int lane = tid & 63;
  const int w = __builtin_amdgcn_readfirstlane(tid >> 6);
  const int col = lane & 15;
  const int quad = lane >> 4;
  const int sp = blockIdx.x & 3;                   // split id
  const int sg = blockIdx.x >> 2;                  // sample group
  const int sbase = sg * 64 + w * 16;
  const int nbase0 = sp * CPS;

  // --- Phase A: W slice conversion (flat, disjoint across blocks) ---
  {
    const float4* wsrc = (const float4*)wts;
    ushort4* wdst = (ushort4*)wb;
    #pragma unroll
    for (int r = 0; r < 2; ++r) {
      const int i4 = blockIdx.x * 512 + r * 256 + tid;
      float4 v = wsrc[i4];
      ushort4 o;
      o.x = bf16_rne(v.x); o.y = bf16_rne(v.y);
      o.z = bf16_rne(v.z); o.w = bf16_rne(v.w);
      wdst[i4] = o;
    }
  }

  // --- Phase B: half-norms for this split (formula identical to R11 prep) ---
  #pragma unroll
  for (int r = 0; r < 2; ++r) {
    const int rl = r * 256 + tid;
    if (rl < CPS) {
      const float4* cp4 = (const float4*)(ctrs + (size_t)(nbase0 + rl) * D_IN);
      float a = 0.f;
      #pragma unroll
      for (int q = 0; q < 8; ++q) {
        float4 c = cp4[q];
        a += c.x * c.x + c.y * c.y + c.z * c.z + c.w * c.w;
      }
      s_hb[rl] = -0.5f * a;
    }
  }

  // --- A-frag: x row (sbase+col), chunk quad -- fp32 load + RNE (once) ---
  bf16x8 ah;
  {
    const float4* xp =
        (const float4*)(x + (size_t)(sbase + col) * D_IN + quad * 8);
    float4 v0 = xp[0], v1 = xp[1];
    float xf[8] = {v0.x, v0.y, v0.z, v0.w, v1.x, v1.y, v1.z, v1.w};
    #pragma unroll
    for (int i = 0; i < 8; ++i) ah[i] = (short)bf16_rne(xf[i]);
  }
  __syncthreads();

  // --- Phase C: tile loop ---
  unsigned ls[4][4];
  #pragma unroll
  for (int r = 0; r < 4; ++r)
    #pragma unroll
    for (int e = 0; e < 4; ++e) ls[r][e] = 0u;   // real keys always > 0

  #pragma unroll 2
  for (int t = 0; t < TILES; ++t) {
    const int rl = t * 16 + col;                  // local center row
    const float4* cp =
        (const float4*)(ctrs + (size_t)(nbase0 + rl) * D_IN + quad * 8);
    float4 c0 = cp[0], c1 = cp[1];
    float cf[8] = {c0.x, c0.y, c0.z, c0.w, c1.x, c1.y, c1.z, c1.w};
    bf16x8 bh;
    #pragma unroll
    for (int i = 0; i < 8; ++i) bh[i] = (short)bf16_rne(cf[i]);
    const float hbv = s_hb[rl];                   // broadcast across quads

    f32x4 acc = {0.f, 0.f, 0.f, 0.f};
    acc = __builtin_amdgcn_mfma_f32_16x16x32_bf16(ah, bh, acc, 0, 0, 0);

    const unsigned tc = (unsigned)rl;             // 9-bit local center id
    #pragma unroll
    for (int r = 0; r < 4; ++r) {
      const float u = acc[r] + hbv;               // score (maximize)
      unsigned b = __float_as_uint(u);
      unsigned m = b ^ ((unsigned)((int)b >> 31) | 0x80000000u);  // monotone
      unsigned key = (m & 0xFFFFFE00u) | tc;
      unsigned t0 = umin_u(ls[r][0], key); ls[r][0] = umax_u(ls[r][0], key);
      unsigned t1 = umin_u(ls[r][1], t0);  ls[r][1] = umax_u(ls[r][1], t0);
      unsigned t2 = umin_u(ls[r][2], t1);  ls[r][2] = umax_u(ls[r][2], t1);
      ls[r][3] = umax_u(ls[r][3], t2);
    }
  }

  // --- Phase D: stage + per-wave subset top-6 -> pool ---
  #pragma unroll
  for (int r = 0; r < 4; ++r) {
    const int row = quad * 4 + r;
    *(uint4*)&s_cand[w][row][col][0] =
        make_uint4(ls[r][0], ls[r][1], ls[r][2], ls[r][3]);
  }
  __syncthreads();

  if (lane < 32) {
    const int sl = lane >> 1;        // local sample 0..15 (this wave's group)
    const int half = lane & 1;       // col half
    const int chh = half * 8;
    unsigned q0 = 0, q1 = 0, q2 = 0, q3 = 0, q4 = 0, q5 = 0;
    #pragma unroll
    for (int c2 = 0; c2 < 8; ++c2) {
      uint4 kv = *(const uint4*)&s_cand[w][sl][chh + c2][0];
      unsigned ks[4] = {kv.x, kv.y, kv.z, kv.w};
      #pragma unroll
      for (int e = 0; e < 4; ++e) {
        unsigned key = ks[e];
        unsigned t0 = umin_u(q0, key); q0 = umax_u(q0, key);
        unsigned t1 = umin_u(q1, t0);  q1 = umax_u(q1, t0);
        unsigned t2 = umin_u(q2, t1);  q2 = umax_u(q2, t1);
        unsigned t3 = umin_u(q3, t2);  q3 = umax_u(q3, t2);
        unsigned t4 = umin_u(q4, t3);  q4 = umax_u(q4, t3);
        q5 = umax_u(q5, t4);
      }
    }
    // layout identical to R11: pool[s*48 + (sp*2+half)*6 + i]
    unsigned* op = pool + (size_t)(sbase + sl) * POOL + (sp * 2 + half) * 6;
    op[0] = q0; op[1] = q1; op[2] = q2;
    op[3] = q3; op[4] = q4; op[5] = q5;
  }
}

// ---------------- Kernel 2: fp64 refine + gather-apply (bf16 W) --------------
// (byte-identical to R11's passing k_apply)
#define K2_BLOCK 256
#define K2_SAMPLES 8

__global__ __launch_bounds__(K2_BLOCK) void k_apply(
    const float* __restrict__ x, const float* __restrict__ ctrs,
    const unsigned short* __restrict__ wb, const float* __restrict__ offs,
    const unsigned* __restrict__ pool, float* __restrict__ y)
{
  __shared__ double s_pd2[K2_SAMPLES][POOL];
  __shared__ int    s_pix[K2_SAMPLES][POOL];
  __shared__ int    s_sel[K2_SAMPLES][KNN];
  __shared__ float  s_diff[K2_SAMPLES][KNN][D_IN + 1];
  __shared__ float4 s_part[K2_SAMPLES][KNN][D_OUT / 4];

  const int tid = threadIdx.x;
  const int sbase = blockIdx.x * K2_SAMPLES;

  for (int c = tid; c < K2_SAMPLES * POOL; c += K2_BLOCK) {
    const int sl = c / POOL;
    const int p = c - sl * POOL;
    const unsigned key = pool[(size_t)(sbase + sl) * POOL + p];
    const int wv = p / 12;
    const int j = wv * CPS + (int)(key & 0x1FFu);
    const float4* xp4 = (const float4*)(x + (size_t)(sbase + sl) * D_IN);
    const float4* cp4 = (const float4*)(ctrs + (size_t)j * D_IN);
    double d2a = 0.0, d2b = 0.0;
    #pragma unroll
    for (int q = 0; q < 8; ++q) {
      float4 cv = cp4[q];
      float4 xv = xp4[q];
      double df0 = (double)xv.x - (double)cv.x;
      double df1 = (double)xv.y - (double)cv.y;
      double df2 = (double)xv.z - (double)cv.z;
      double df3 = (double)xv.w - (double)cv.w;
      d2a = fma(df0, df0, d2a);
      d2b = fma(df1, df1, d2b);
      d2a = fma(df2, df2, d2a);
      d2b = fma(df3, df3, d2b);
    }
    s_pd2[sl][p] = d2a + d2b;
    s_pix[sl][p] = j;
  }
  __syncthreads();

  if (tid < K2_SAMPLES) {
    double bd[4]; int b4[4];
    #pragma unroll
    for (int e = 0; e < 4; ++e) { bd[e] = 1e300; b4[e] = 0x7fffffff; }
    for (int m = 0; m < POOL; ++m) {
      const double d2 = s_pd2[tid][m];
      const int j = s_pix[tid][m];
      bool ins = (d2 < bd[3]) || (d2 == bd[3] && j < b4[3]);
      if (ins) {
        bd[3] = d2; b4[3] = j;
        #pragma unroll
        for (int q = 3; q > 0; --q) {
          bool sw = (bd[q] < bd[q - 1]) ||
                    (bd[q] == bd[q - 1] && b4[q] < b4[q - 1]);
          if (sw) {
            double td = bd[q]; bd[q] = bd[q - 1]; bd[q - 1] = td;
            int    tj = b4[q]; b4[q] = b4[q - 1]; b4[q - 1] = tj;
          }
        }
      }
    }
    #pragma unroll
    for (int q = 0; q < 4; ++q) s_sel[tid][q] = b4[q];
  }
  __syncthreads();

  #pragma unroll
  for (int r = 0; r < K2_SAMPLES * KNN * D_IN / K2_BLOCK; ++r) {
    int v = r * K2_BLOCK + tid;
    int d = v & 31; int p = v >> 5;
    int sl = p >> 2; int j = p & 3;
    int f = s_sel[sl][j];
    s_diff[sl][j][d] =
        x[(size_t)(sbase + sl) * D_IN + d] - ctrs[(size_t)f * D_IN + d];
  }
  __syncthreads();

  const int sl = tid >> 5;
  const int j  = (tid >> 3) & 3;
  const int eq = tid & 7;
  const int s = sbase + sl;

  const int f = s_sel[sl][j];
  const uint2* wp = (const uint2*)(wb + (size_t)f * (D_IN * D_OUT));
  float4 acc = ((const float4*)(offs + (size_t)f * D_OUT))[eq];
  #pragma unroll
  for (int d = 0; d < D_IN; ++d) {
    uint2 wv = wp[d * 8 + eq];
    float w0 = __uint_as_float(wv.x << 16);
    float w1 = __uint_as_float(wv.x & 0xFFFF0000u);
    float w2 = __uint_as_float(wv.y << 16);
    float w3 = __uint_as_float(wv.y & 0xFFFF0000u);
    float xc = s_diff[sl][j][d];
    acc.x = fmaf(xc, w0, acc.x);
    acc.y = fmaf(xc, w1, acc.y);
    acc.z = fmaf(xc, w2, acc.z);
    acc.w = fmaf(xc, w3, acc.w);
  }
  s_part[sl][j][eq] = acc;
  __syncthreads();

  if (j == 0) {
    float4 a = s_part[sl][0][eq], b = s_part[sl][1][eq];
    float4 c = s_part[sl][2][eq], e = s_part[sl][3][eq];
    float4 o;
    o.x = (a.x + b.x) + (c.x + e.x);
    o.y = (a.y + b.y) + (c.y + e.y);
    o.z = (a.z + b.z) + (c.z + e.z);
    o.w = (a.w + b.w) + (c.w + e.w);
    ((float4*)(y + (size_t)s * D_OUT))[eq] = o;
  }
}

// ---------------- launch: 2 dispatches ---------------------------------------
extern "C" void kernel_launch(void* const* d_in, const int* in_sizes, int n_in,
                              void* d_out, int out_size, void* d_ws, size_t ws_size,
                              hipStream_t stream) {
  const float* x    = (const float*)d_in[0];
  const float* ctrs = (const float*)d_in[1];
  const float* wts  = (const float*)d_in[2];
  const float* offs = (const float*)d_in[3];
  float* y = (float*)d_out;

  char* ws = (char*)d_ws;
  unsigned short* wb = (unsigned short*)(ws + OFF_WB);
  unsigned*     pool = (unsigned*)(ws + OFF_POOL);

  k_topk<<<(N_SMPS / 64) * SPLITS, 256, 0, stream>>>(x, ctrs, wts, wb, pool);
  k_apply<<<N_SMPS / K2_SAMPLES, K2_BLOCK, 0, stream>>>(x, ctrs, wb, offs,
                                                        pool, y);
}

// Round 13
// 115.351 us; speedup vs baseline: 1.1864x; 1.1864x over previous
//
#include <hip/hip_runtime.h>
#include <math.h>

typedef short bf16x8 __attribute__((ext_vector_type(8)));
typedef float f32x4  __attribute__((ext_vector_type(4)));

#define N_SMPS 16384
#define N_FCNS 2048
#define D_IN 32
#define D_OUT 32
#define KNN 4
#define SPLITS 4
#define CPS 512            // centers per split (one wave per split)
#define TILES 32           // CPS / 16
#define POOL 48            // 8 subsets x top-6, all-distinct candidates

__device__ __forceinline__ unsigned umin_u(unsigned a, unsigned b) { return a < b ? a : b; }
__device__ __forceinline__ unsigned umax_u(unsigned a, unsigned b) { return a > b ? a : b; }

// round-to-nearest-even fp32 -> bf16
__device__ __forceinline__ unsigned short bf16_rne(float f) {
  unsigned b = __float_as_uint(f);
  unsigned r = b + 0x7FFFu + ((b >> 16) & 1u);
  return (unsigned short)(r >> 16);
}

// ---------------- ws layout (bytes) ------------------------------------------
// xh 1MB | ch 128K | hb 8K | wb 4MB | pool 3MB  -> ~8.2 MB
#define OFF_XH   0u
#define OFF_CH   1048576u
#define OFF_HB   (OFF_CH + 131072u)
#define OFF_WB   (OFF_HB + 8192u)
#define OFF_POOL (OFF_WB + 4194304u)

#define NX4 (N_SMPS * D_IN / 4)            // 131072
#define NC4 (N_FCNS * D_IN / 4)            // 16384
#define NW4 (N_FCNS * D_IN * D_OUT / 4)    // 524288
#define NTOT (NX4 + NC4 + NW4)             // 671744 = 2624 * 256

// ---------------- Kernel 0: bf16 RNE conversion (x, ctrs, W) + norms ---------
// (byte-identical to R11's passing k_prep)
__global__ __launch_bounds__(256) void k_prep(
    const float* __restrict__ x, const float* __restrict__ ctrs,
    const float* __restrict__ wts,
    unsigned short* __restrict__ xh, unsigned short* __restrict__ ch,
    unsigned short* __restrict__ wb, float* __restrict__ hb)
{
  const int gt = blockIdx.x * 256 + threadIdx.x;
  const float* src; unsigned short* dst; int i4;
  if (gt < NX4)            { src = x;    dst = xh; i4 = gt; }
  else if (gt < NX4 + NC4) { src = ctrs; dst = ch; i4 = gt - NX4; }
  else                     { src = wts;  dst = wb; i4 = gt - (NX4 + NC4); }
  float4 v = ((const float4*)src)[i4];
  ushort4 o;
  o.x = bf16_rne(v.x); o.y = bf16_rne(v.y);
  o.z = bf16_rne(v.z); o.w = bf16_rne(v.w);
  ((ushort4*)dst)[i4] = o;

  if (gt < N_FCNS) {   // fp32-exact half-norms from original ctrs
    const float4* cp4 = (const float4*)(ctrs + (size_t)gt * D_IN);
    float a = 0.f;
    #pragma unroll
    for (int q = 0; q < 8; ++q) {
      float4 c = cp4[q];
      a += c.x * c.x + c.y * c.y + c.z * c.z + c.w * c.w;
    }
    hb[gt] = -0.5f * a;
  }
}

// ---------------- Kernel 1: MFMA topk -> 48-key pool (2-deep prefetch) -------
// R11 structure (pre-converted bf16, wave = split, no fp64 tail) + register
// double-buffer: tiles t+2/t+3's B-frags and hb loaded (wrap-indexed) before
// processing t/t+1 -- ~360 cyc of ladder work covers the ~200-300 cyc L2
// latency that capped R11/R12 at VALUBusy ~37%.
__global__ __launch_bounds__(256) void k_topk(
    const unsigned short* __restrict__ xh, const unsigned short* __restrict__ ch,
    const float* __restrict__ hb, unsigned* __restrict__ pool)
{
  __shared__ unsigned s_cand[SPLITS][16][16][4];   // 16 KB

  const int tid = threadIdx.x;
  const int lane = tid & 63;
  const int w = __builtin_amdgcn_readfirstlane(tid >> 6);  // wave = split
  const int col = lane & 15;
  const int quad = lane >> 4;
  const int sbase = blockIdx.x * 16;
  const int nbase0 = w * CPS;

  // A-frag: lane holds A[m=col][k=quad*8+j], 16 B contiguous
  const bf16x8 ah =
      *(const bf16x8*)(xh + (size_t)(sbase + col) * D_IN + quad * 8);

  unsigned ls[4][4];
  #pragma unroll
  for (int r = 0; r < 4; ++r)
    #pragma unroll
    for (int e = 0; e < 4; ++e) ls[r][e] = 0u;   // real keys always > 0

  // per-tile loaders (per-lane vector loads; addresses affine in t)
  const unsigned short* chb = ch + (size_t)nbase0 * D_IN + (size_t)col * D_IN + quad * 8;
  #define BLOAD(t) (*(const bf16x8*)(chb + (size_t)(t) * 16 * D_IN))
  #define HLOAD(t) (hb[nbase0 + (t) * 16 + col])

  bf16x8 bh0 = BLOAD(0), bh1 = BLOAD(1);
  float  hv0 = HLOAD(0), hv1 = HLOAD(1);

  for (int t = 0; t < TILES; t += 2) {
    // prefetch t+2 / t+3 (wrap at end; wrapped values unused)
    const int tp0 = (t + 2) & (TILES - 1);
    const int tp1 = (t + 3) & (TILES - 1);
    bf16x8 bhn0 = BLOAD(tp0), bhn1 = BLOAD(tp1);
    float  hvn0 = HLOAD(tp0), hvn1 = HLOAD(tp1);

    // ---- tile t ----
    {
      f32x4 acc = {0.f, 0.f, 0.f, 0.f};
      acc = __builtin_amdgcn_mfma_f32_16x16x32_bf16(ah, bh0, acc, 0, 0, 0);
      const unsigned tc = (unsigned)(t * 16 + col);
      #pragma unroll
      for (int r = 0; r < 4; ++r) {
        const float u = acc[r] + hv0;
        unsigned b = __float_as_uint(u);
        unsigned m = b ^ ((unsigned)((int)b >> 31) | 0x80000000u);
        unsigned key = (m & 0xFFFFFE00u) | tc;
        unsigned t0 = umin_u(ls[r][0], key); ls[r][0] = umax_u(ls[r][0], key);
        unsigned t1 = umin_u(ls[r][1], t0);  ls[r][1] = umax_u(ls[r][1], t0);
        unsigned t2 = umin_u(ls[r][2], t1);  ls[r][2] = umax_u(ls[r][2], t1);
        ls[r][3] = umax_u(ls[r][3], t2);
      }
    }
    // ---- tile t+1 ----
    {
      f32x4 acc = {0.f, 0.f, 0.f, 0.f};
      acc = __builtin_amdgcn_mfma_f32_16x16x32_bf16(ah, bh1, acc, 0, 0, 0);
      const unsigned tc = (unsigned)((t + 1) * 16 + col);
      #pragma unroll
      for (int r = 0; r < 4; ++r) {
        const float u = acc[r] + hv1;
        unsigned b = __float_as_uint(u);
        unsigned m = b ^ ((unsigned)((int)b >> 31) | 0x80000000u);
        unsigned key = (m & 0xFFFFFE00u) | tc;
        unsigned t0 = umin_u(ls[r][0], key); ls[r][0] = umax_u(ls[r][0], key);
        unsigned t1 = umin_u(ls[r][1], t0);  ls[r][1] = umax_u(ls[r][1], t0);
        unsigned t2 = umin_u(ls[r][2], t1);  ls[r][2] = umax_u(ls[r][2], t1);
        ls[r][3] = umax_u(ls[r][3], t2);
      }
    }
    bh0 = bhn0; bh1 = bhn1; hv0 = hvn0; hv1 = hvn1;
  }
  #undef BLOAD
  #undef HLOAD

  #pragma unroll
  for (int r = 0; r < 4; ++r) {
    const int row = quad * 4 + r;
    *(uint4*)&s_cand[w][row][col][0] =
        make_uint4(ls[r][0], ls[r][1], ls[r][2], ls[r][3]);
  }
  __syncthreads();

  // subset top-6: thread t<128: sample t>>3, subset t&7 (wave g>>1, half g&1)
  if (tid < 128) {
    const int sl = tid >> 3;
    const int g  = tid & 7;
    const int wv = g >> 1;
    const int chh = (g & 1) * 8;
    unsigned q0 = 0, q1 = 0, q2 = 0, q3 = 0, q4 = 0, q5 = 0;
    #pragma unroll
    for (int c2 = 0; c2 < 8; ++c2) {
      uint4 kv = *(const uint4*)&s_cand[wv][sl][chh + c2][0];
      unsigned ks[4] = {kv.x, kv.y, kv.z, kv.w};
      #pragma unroll
      for (int e = 0; e < 4; ++e) {
        unsigned key = ks[e];
        unsigned t0 = umin_u(q0, key); q0 = umax_u(q0, key);
        unsigned t1 = umin_u(q1, t0);  q1 = umax_u(q1, t0);
        unsigned t2 = umin_u(q2, t1);  q2 = umax_u(q2, t1);
        unsigned t3 = umin_u(q3, t2);  q3 = umax_u(q3, t2);
        unsigned t4 = umin_u(q4, t3);  q4 = umax_u(q4, t3);
        q5 = umax_u(q5, t4);
      }
    }
    unsigned* op = pool + (size_t)(sbase + sl) * POOL + g * 6;
    op[0] = q0; op[1] = q1; op[2] = q2;
    op[3] = q3; op[4] = q4; op[5] = q5;
  }
}

// ---------------- Kernel 2: fp64 refine + gather-apply (bf16 W) --------------
// (byte-identical to R11's passing k_apply)
#define K2_BLOCK 256
#define K2_SAMPLES 8

__global__ __launch_bounds__(K2_BLOCK) void k_apply(
    const float* __restrict__ x, const float* __restrict__ ctrs,
    const unsigned short* __restrict__ wb, const float* __restrict__ offs,
    const unsigned* __restrict__ pool, float* __restrict__ y)
{
  __shared__ double s_pd2[K2_SAMPLES][POOL];
  __shared__ int    s_pix[K2_SAMPLES][POOL];
  __shared__ int    s_sel[K2_SAMPLES][KNN];
  __shared__ float  s_diff[K2_SAMPLES][KNN][D_IN + 1];
  __shared__ float4 s_part[K2_SAMPLES][KNN][D_OUT / 4];

  const int tid = threadIdx.x;
  const int sbase = blockIdx.x * K2_SAMPLES;

  for (int c = tid; c < K2_SAMPLES * POOL; c += K2_BLOCK) {
    const int sl = c / POOL;
    const int p = c - sl * POOL;
    const unsigned key = pool[(size_t)(sbase + sl) * POOL + p];
    const int wv = p / 12;
    const int j = wv * CPS + (int)(key & 0x1FFu);
    const float4* xp4 = (const float4*)(x + (size_t)(sbase + sl) * D_IN);
    const float4* cp4 = (const float4*)(ctrs + (size_t)j * D_IN);
    double d2a = 0.0, d2b = 0.0;
    #pragma unroll
    for (int q = 0; q < 8; ++q) {
      float4 cv = cp4[q];
      float4 xv = xp4[q];
      double df0 = (double)xv.x - (double)cv.x;
      double df1 = (double)xv.y - (double)cv.y;
      double df2 = (double)xv.z - (double)cv.z;
      double df3 = (double)xv.w - (double)cv.w;
      d2a = fma(df0, df0, d2a);
      d2b = fma(df1, df1, d2b);
      d2a = fma(df2, df2, d2a);
      d2b = fma(df3, df3, d2b);
    }
    s_pd2[sl][p] = d2a + d2b;
    s_pix[sl][p] = j;
  }
  __syncthreads();

  if (tid < K2_SAMPLES) {
    double bd[4]; int b4[4];
    #pragma unroll
    for (int e = 0; e < 4; ++e) { bd[e] = 1e300; b4[e] = 0x7fffffff; }
    for (int m = 0; m < POOL; ++m) {
      const double d2 = s_pd2[tid][m];
      const int j = s_pix[tid][m];
      bool ins = (d2 < bd[3]) || (d2 == bd[3] && j < b4[3]);
      if (ins) {
        bd[3] = d2; b4[3] = j;
        #pragma unroll
        for (int q = 3; q > 0; --q) {
          bool sw = (bd[q] < bd[q - 1]) ||
                    (bd[q] == bd[q - 1] && b4[q] < b4[q - 1]);
          if (sw) {
            double td = bd[q]; bd[q] = bd[q - 1]; bd[q - 1] = td;
            int    tj = b4[q]; b4[q] = b4[q - 1]; b4[q - 1] = tj;
          }
        }
      }
    }
    #pragma unroll
    for (int q = 0; q < 4; ++q) s_sel[tid][q] = b4[q];
  }
  __syncthreads();

  #pragma unroll
  for (int r = 0; r < K2_SAMPLES * KNN * D_IN / K2_BLOCK; ++r) {
    int v = r * K2_BLOCK + tid;
    int d = v & 31; int p = v >> 5;
    int sl = p >> 2; int j = p & 3;
    int f = s_sel[sl][j];
    s_diff[sl][j][d] =
        x[(size_t)(sbase + sl) * D_IN + d] - ctrs[(size_t)f * D_IN + d];
  }
  __syncthreads();

  const int sl = tid >> 5;
  const int j  = (tid >> 3) & 3;
  const int eq = tid & 7;
  const int s = sbase + sl;

  const int f = s_sel[sl][j];
  const uint2* wp = (const uint2*)(wb + (size_t)f * (D_IN * D_OUT));
  float4 acc = ((const float4*)(offs + (size_t)f * D_OUT))[eq];
  #pragma unroll
  for (int d = 0; d < D_IN; ++d) {
    uint2 wv = wp[d * 8 + eq];
    float w0 = __uint_as_float(wv.x << 16);
    float w1 = __uint_as_float(wv.x & 0xFFFF0000u);
    float w2 = __uint_as_float(wv.y << 16);
    float w3 = __uint_as_float(wv.y & 0xFFFF0000u);
    float xc = s_diff[sl][j][d];
    acc.x = fmaf(xc, w0, acc.x);
    acc.y = fmaf(xc, w1, acc.y);
    acc.z = fmaf(xc, w2, acc.z);
    acc.w = fmaf(xc, w3, acc.w);
  }
  s_part[sl][j][eq] = acc;
  __syncthreads();

  if (j == 0) {
    float4 a = s_part[sl][0][eq], b = s_part[sl][1][eq];
    float4 c = s_part[sl][2][eq], e = s_part[sl][3][eq];
    float4 o;
    o.x = (a.x + b.x) + (c.x + e.x);
    o.y = (a.y + b.y) + (c.y + e.y);
    o.z = (a.z + b.z) + (c.z + e.z);
    o.w = (a.w + b.w) + (c.w + e.w);
    ((float4*)(y + (size_t)s * D_OUT))[eq] = o;
  }
}

// ---------------- launch: 3 dispatches ---------------------------------------
extern "C" void kernel_launch(void* const* d_in, const int* in_sizes, int n_in,
                              void* d_out, int out_size, void* d_ws, size_t ws_size,
                              hipStream_t stream) {
  const float* x    = (const float*)d_in[0];
  const float* ctrs = (const float*)d_in[1];
  const float* wts  = (const float*)d_in[2];
  const float* offs = (const float*)d_in[3];
  float* y = (float*)d_out;

  char* ws = (char*)d_ws;
  unsigned short* xh = (unsigned short*)(ws + OFF_XH);
  unsigned short* ch = (unsigned short*)(ws + OFF_CH);
  float*          hb = (float*)(ws + OFF_HB);
  unsigned short* wb = (unsigned short*)(ws + OFF_WB);
  unsigned*     pool = (unsigned*)(ws + OFF_POOL);

  k_prep<<<NTOT / 256, 256, 0, stream>>>(x, ctrs, wts, xh, ch, wb, hb);
  k_topk<<<N_SMPS / 16, 256, 0, stream>>>(xh, ch, hb, pool);
  k_apply<<<N_SMPS / K2_SAMPLES, K2_BLOCK, 0, stream>>>(x, ctrs, wb, offs,
                                                        pool, y);
}

// Round 15
// 114.523 us; speedup vs baseline: 1.1950x; 1.0072x over previous
//
#include <hip/hip_runtime.h>
#include <math.h>

typedef short bf16x8 __attribute__((ext_vector_type(8)));
typedef float f32x4  __attribute__((ext_vector_type(4)));

#define N_SMPS 16384
#define N_FCNS 2048
#define D_IN 32
#define D_OUT 32
#define KNN 4
#define SPLITS 4
#define CPS 512            // centers per split (one wave per split)
#define TILES 32           // CPS / 16
#define POOL 48            // 8 subsets x top-6, all-distinct candidates
#define SMP 16             // samples per block

__device__ __forceinline__ unsigned umin_u(unsigned a, unsigned b) { return a < b ? a : b; }
__device__ __forceinline__ unsigned umax_u(unsigned a, unsigned b) { return a > b ? a : b; }

// round-to-nearest-even fp32 -> bf16
__device__ __forceinline__ unsigned short bf16_rne(float f) {
  unsigned b = __float_as_uint(f);
  unsigned r = b + 0x7FFFu + ((b >> 16) & 1u);
  return (unsigned short)(r >> 16);
}

// ---------------- ws layout (bytes) ------------------------------------------
// xh 1MB | ch 128K | hb 8K | wb 4MB   -> ~5.2 MB (no pool: stays in LDS)
#define OFF_XH   0u
#define OFF_CH   1048576u
#define OFF_HB   (OFF_CH + 131072u)
#define OFF_WB   (OFF_HB + 8192u)

#define NX4 (N_SMPS * D_IN / 4)            // 131072
#define NC4 (N_FCNS * D_IN / 4)            // 16384
#define NW4 (N_FCNS * D_IN * D_OUT / 4)    // 524288
#define NTOT (NX4 + NC4 + NW4)             // 671744 = 2624 * 256

// ---------------- Kernel 0: bf16 RNE conversion (x, ctrs, W) + norms ---------
// (byte-identical to R13's passing k_prep)
__global__ __launch_bounds__(256) void k_prep(
    const float* __restrict__ x, const float* __restrict__ ctrs,
    const float* __restrict__ wts,
    unsigned short* __restrict__ xh, unsigned short* __restrict__ ch,
    unsigned short* __restrict__ wb, float* __restrict__ hb)
{
  const int gt = blockIdx.x * 256 + threadIdx.x;
  const float* src; unsigned short* dst; int i4;
  if (gt < NX4)            { src = x;    dst = xh; i4 = gt; }
  else if (gt < NX4 + NC4) { src = ctrs; dst = ch; i4 = gt - NX4; }
  else                     { src = wts;  dst = wb; i4 = gt - (NX4 + NC4); }
  float4 v = ((const float4*)src)[i4];
  ushort4 o;
  o.x = bf16_rne(v.x); o.y = bf16_rne(v.y);
  o.z = bf16_rne(v.z); o.w = bf16_rne(v.w);
  ((ushort4*)dst)[i4] = o;

  if (gt < N_FCNS) {   // fp32-exact half-norms from original ctrs
    const float4* cp4 = (const float4*)(ctrs + (size_t)gt * D_IN);
    float a = 0.f;
    #pragma unroll
    for (int q = 0; q < 8; ++q) {
      float4 c = cp4[q];
      a += c.x * c.x + c.y * c.y + c.z * c.z + c.w * c.w;
    }
    hb[gt] = -0.5f * a;
  }
}

// ---------------- Kernel 1: MEGA -- topk + fp64 refine + gather-apply --------
// Block = 16 samples, 4 waves = 4 splits. Phases (raw char LDS arena overlay;
// NO union of vector types -- that construct core-dumped in R14):
//  1. R13's MFMA topk (prefetch) -> per-subset top-6 keys -> s_pool (LDS)
//  2. fp64 exact distances for 16x48 pool entries (proven math/tie-break)
//  3. per-sample top-4 -> s_sel
//  4/5. diff staging + bf16-W gather-apply (R11's proven arithmetic)
// Plain launch_bounds(256): no min-waves pressure -> no fp64 spill (R10 lesson).
__global__ __launch_bounds__(256) void k_mega(
    const unsigned short* __restrict__ xh, const unsigned short* __restrict__ ch,
    const float* __restrict__ hb,
    const float* __restrict__ x, const float* __restrict__ ctrs,
    const unsigned short* __restrict__ wb, const float* __restrict__ offs,
    float* __restrict__ y)
{
  // arena: phase1 cand = 4*16*16*4 u32 = 16384 B;
  //        phase4/5 diff = 16*4*33 f32 = 8448 B, part = 16*4*8 f32x4 = 8192 B
  __shared__ __align__(16) char u_mem[16640];
  __shared__ unsigned s_pool[SMP][POOL];                       // 3 KB
  __shared__ double   s_pd2[SMP][POOL];                        // 6 KB
  __shared__ int      s_pix[SMP][POOL];                        // 3 KB
  __shared__ int      s_sel[SMP][KNN];                         // 256 B

  unsigned* s_cand = (unsigned*)u_mem;          // [w][row][col][e] flattened
  float*    s_diff = (float*)u_mem;             // [sl][j][33] flattened
  float4*   s_part = (float4*)(u_mem + 8448);   // [sl][j][8] flattened

  const int tid = threadIdx.x;
  const int lane = tid & 63;
  const int w = __builtin_amdgcn_readfirstlane(tid >> 6);  // wave = split
  const int col = lane & 15;
  const int quad = lane >> 4;
  const int sbase = blockIdx.x * SMP;
  const int nbase0 = w * CPS;

  // ---- Phase 1: MFMA topk (identical key construction to R13) ----
  const bf16x8 ah =
      *(const bf16x8*)(xh + (size_t)(sbase + col) * D_IN + quad * 8);

  unsigned ls[4][4];
  #pragma unroll
  for (int r = 0; r < 4; ++r)
    #pragma unroll
    for (int e = 0; e < 4; ++e) ls[r][e] = 0u;   // real keys always > 0

  const unsigned short* chb =
      ch + (size_t)nbase0 * D_IN + (size_t)col * D_IN + quad * 8;
  #define BLOAD(t) (*(const bf16x8*)(chb + (size_t)(t) * 16 * D_IN))
  #define HLOAD(t) (hb[nbase0 + (t) * 16 + col])

  bf16x8 bh0 = BLOAD(0), bh1 = BLOAD(1);
  float  hv0 = HLOAD(0), hv1 = HLOAD(1);

  for (int t = 0; t < TILES; t += 2) {
    const int tp0 = (t + 2) & (TILES - 1);
    const int tp1 = (t + 3) & (TILES - 1);
    bf16x8 bhn0 = BLOAD(tp0), bhn1 = BLOAD(tp1);
    float  hvn0 = HLOAD(tp0), hvn1 = HLOAD(tp1);
    {
      f32x4 acc = {0.f, 0.f, 0.f, 0.f};
      acc = __builtin_amdgcn_mfma_f32_16x16x32_bf16(ah, bh0, acc, 0, 0, 0);
      const unsigned tc = (unsigned)(t * 16 + col);
      #pragma unroll
      for (int r = 0; r < 4; ++r) {
        const float uu = acc[r] + hv0;
        unsigned b = __float_as_uint(uu);
        unsigned m = b ^ ((unsigned)((int)b >> 31) | 0x80000000u);
        unsigned key = (m & 0xFFFFFE00u) | tc;
        unsigned t0 = umin_u(ls[r][0], key); ls[r][0] = umax_u(ls[r][0], key);
        unsigned t1 = umin_u(ls[r][1], t0);  ls[r][1] = umax_u(ls[r][1], t0);
        unsigned t2 = umin_u(ls[r][2], t1);  ls[r][2] = umax_u(ls[r][2], t1);
        ls[r][3] = umax_u(ls[r][3], t2);
      }
    }
    {
      f32x4 acc = {0.f, 0.f, 0.f, 0.f};
      acc = __builtin_amdgcn_mfma_f32_16x16x32_bf16(ah, bh1, acc, 0, 0, 0);
      const unsigned tc = (unsigned)((t + 1) * 16 + col);
      #pragma unroll
      for (int r = 0; r < 4; ++r) {
        const float uu = acc[r] + hv1;
        unsigned b = __float_as_uint(uu);
        unsigned m = b ^ ((unsigned)((int)b >> 31) | 0x80000000u);
        unsigned key = (m & 0xFFFFFE00u) | tc;
        unsigned t0 = umin_u(ls[r][0], key); ls[r][0] = umax_u(ls[r][0], key);
        unsigned t1 = umin_u(ls[r][1], t0);  ls[r][1] = umax_u(ls[r][1], t0);
        unsigned t2 = umin_u(ls[r][2], t1);  ls[r][2] = umax_u(ls[r][2], t1);
        ls[r][3] = umax_u(ls[r][3], t2);
      }
    }
    bh0 = bhn0; bh1 = bhn1; hv0 = hvn0; hv1 = hvn1;
  }
  #undef BLOAD
  #undef HLOAD

  #pragma unroll
  for (int r = 0; r < 4; ++r) {
    const int row = quad * 4 + r;
    *(uint4*)&s_cand[(((w * 16) + row) * 16 + col) * 4] =
        make_uint4(ls[r][0], ls[r][1], ls[r][2], ls[r][3]);
  }
  __syncthreads();

  // subset top-6 -> s_pool (same mapping as R13: subset g = wave*2 + half)
  if (tid < 128) {
    const int sl = tid >> 3;
    const int g  = tid & 7;
    const int wv = g >> 1;
    const int chh = (g & 1) * 8;
    unsigned q0 = 0, q1 = 0, q2 = 0, q3 = 0, q4 = 0, q5 = 0;
    #pragma unroll
    for (int c2 = 0; c2 < 8; ++c2) {
      uint4 kv = *(const uint4*)&s_cand[(((wv * 16) + sl) * 16 + chh + c2) * 4];
      unsigned ks[4] = {kv.x, kv.y, kv.z, kv.w};
      #pragma unroll
      for (int e = 0; e < 4; ++e) {
        unsigned key = ks[e];
        unsigned t0 = umin_u(q0, key); q0 = umax_u(q0, key);
        unsigned t1 = umin_u(q1, t0);  q1 = umax_u(q1, t0);
        unsigned t2 = umin_u(q2, t1);  q2 = umax_u(q2, t1);
        unsigned t3 = umin_u(q3, t2);  q3 = umax_u(q3, t2);
        unsigned t4 = umin_u(q4, t3);  q4 = umax_u(q4, t3);
        q5 = umax_u(q5, t4);
      }
    }
    unsigned* op = &s_pool[sl][g * 6];
    op[0] = q0; op[1] = q1; op[2] = q2;
    op[3] = q3; op[4] = q4; op[5] = q5;
  }
  __syncthreads();

  // ---- Phase 2: fp64 exact distances for all 16*48 pool entries ----
  for (int c = tid; c < SMP * POOL; c += 256) {
    const int sl = c / POOL;
    const int p = c - sl * POOL;
    const unsigned key = s_pool[sl][p];
    const int wv = p / 12;
    const int j = wv * CPS + (int)(key & 0x1FFu);
    const float4* xp4 = (const float4*)(x + (size_t)(sbase + sl) * D_IN);
    const float4* cp4 = (const float4*)(ctrs + (size_t)j * D_IN);
    double d2a = 0.0, d2b = 0.0;
    #pragma unroll
    for (int q = 0; q < 8; ++q) {
      float4 cv = cp4[q];
      float4 xv = xp4[q];
      double df0 = (double)xv.x - (double)cv.x;
      double df1 = (double)xv.y - (double)cv.y;
      double df2 = (double)xv.z - (double)cv.z;
      double df3 = (double)xv.w - (double)cv.w;
      d2a = fma(df0, df0, d2a);
      d2b = fma(df1, df1, d2b);
      d2a = fma(df2, df2, d2a);
      d2b = fma(df3, df3, d2b);
    }
    s_pd2[sl][p] = d2a + d2b;
    s_pix[sl][p] = j;
  }
  __syncthreads();

  // ---- Phase 3: per-sample fp64 top-4, np tie-break (proven) ----
  if (tid < SMP) {
    double bd[4]; int b4[4];
    #pragma unroll
    for (int e = 0; e < 4; ++e) { bd[e] = 1e300; b4[e] = 0x7fffffff; }
    for (int m = 0; m < POOL; ++m) {
      const double d2 = s_pd2[tid][m];
      const int j = s_pix[tid][m];
      bool ins = (d2 < bd[3]) || (d2 == bd[3] && j < b4[3]);
      if (ins) {
        bd[3] = d2; b4[3] = j;
        #pragma unroll
        for (int q = 3; q > 0; --q) {
          bool sw = (bd[q] < bd[q - 1]) ||
                    (bd[q] == bd[q - 1] && b4[q] < b4[q - 1]);
          if (sw) {
            double td = bd[q]; bd[q] = bd[q - 1]; bd[q - 1] = td;
            int    tj = b4[q]; b4[q] = b4[q - 1]; b4[q - 1] = tj;
          }
        }
      }
    }
    #pragma unroll
    for (int q = 0; q < 4; ++q) s_sel[tid][q] = b4[q];
  }
  __syncthreads();   // also: s_cand region dead from here; reuse as diff/part

  // ---- Phase 4: diff staging (overlays dead cand region) ----
  #pragma unroll
  for (int r = 0; r < SMP * KNN * D_IN / 256; ++r) {
    int v = r * 256 + tid;
    int d = v & 31; int p = v >> 5;
    int sl = p >> 2; int j = p & 3;
    int f = s_sel[sl][j];
    s_diff[(sl * KNN + j) * (D_IN + 1) + d] =
        x[(size_t)(sbase + sl) * D_IN + d] - ctrs[(size_t)f * D_IN + d];
  }
  __syncthreads();

  // ---- Phase 5: bf16-W gather-apply, 2 slots/thread (same per-slot math) ----
  #pragma unroll
  for (int r = 0; r < 2; ++r) {
    const int slot = r * 256 + tid;
    const int sl = slot >> 5;
    const int j  = (slot >> 3) & 3;
    const int eq = slot & 7;
    const int f = s_sel[sl][j];
    const uint2* wp = (const uint2*)(wb + (size_t)f * (D_IN * D_OUT));
    float4 acc = ((const float4*)(offs + (size_t)f * D_OUT))[eq];
    #pragma unroll
    for (int d = 0; d < D_IN; ++d) {
      uint2 wv = wp[d * 8 + eq];
      float w0 = __uint_as_float(wv.x << 16);
      float w1 = __uint_as_float(wv.x & 0xFFFF0000u);
      float w2 = __uint_as_float(wv.y << 16);
      float w3 = __uint_as_float(wv.y & 0xFFFF0000u);
      float xc = s_diff[(sl * KNN + j) * (D_IN + 1) + d];
      acc.x = fmaf(xc, w0, acc.x);
      acc.y = fmaf(xc, w1, acc.y);
      acc.z = fmaf(xc, w2, acc.z);
      acc.w = fmaf(xc, w3, acc.w);
    }
    s_part[(sl * KNN + j) * 8 + eq] = acc;
  }
  __syncthreads();

  #pragma unroll
  for (int r = 0; r < 2; ++r) {
    const int slot = r * 256 + tid;
    const int sl = slot >> 5;
    const int j  = (slot >> 3) & 3;
    const int eq = slot & 7;
    if (j == 0) {
      float4 a = s_part[(sl * KNN + 0) * 8 + eq];
      float4 b = s_part[(sl * KNN + 1) * 8 + eq];
      float4 c = s_part[(sl * KNN + 2) * 8 + eq];
      float4 e = s_part[(sl * KNN + 3) * 8 + eq];
      float4 o;
      o.x = (a.x + b.x) + (c.x + e.x);
      o.y = (a.y + b.y) + (c.y + e.y);
      o.z = (a.z + b.z) + (c.z + e.z);
      o.w = (a.w + b.w) + (c.w + e.w);
      ((float4*)(y + (size_t)(sbase + sl) * D_OUT))[eq] = o;
    }
  }
}

// ---------------- launch: 2 dispatches ---------------------------------------
extern "C" void kernel_launch(void* const* d_in, const int* in_sizes, int n_in,
                              void* d_out, int out_size, void* d_ws, size_t ws_size,
                              hipStream_t stream) {
  const float* x    = (const float*)d_in[0];
  const float* ctrs = (const float*)d_in[1];
  const float* wts  = (const float*)d_in[2];
  const float* offs = (const float*)d_in[3];
  float* y = (float*)d_out;

  char* ws = (char*)d_ws;
  unsigned short* xh = (unsigned short*)(ws + OFF_XH);
  unsigned short* ch = (unsigned short*)(ws + OFF_CH);
  float*          hb = (float*)(ws + OFF_HB);
  unsigned short* wb = (unsigned short*)(ws + OFF_WB);

  k_prep<<<NTOT / 256, 256, 0, stream>>>(x, ctrs, wts, xh, ch, wb, hb);
  k_mega<<<N_SMPS / SMP, 256, 0, stream>>>(xh, ch, hb, x, ctrs, wb, offs, y);
}

// Round 16
// 110.240 us; speedup vs baseline: 1.2414x; 1.0388x over previous
//
#include <hip/hip_runtime.h>
#include <math.h>

typedef short bf16x8 __attribute__((ext_vector_type(8)));
typedef float f32x4  __attribute__((ext_vector_type(4)));

#define N_SMPS 16384
#define N_FCNS 2048
#define D_IN 32
#define D_OUT 32
#define KNN 4
#define SPLITS 4
#define CPS 512            // centers per split (one wave per split)
#define TILES 32           // CPS / 16
#define POOL 48            // 8 subsets x top-6, all-distinct candidates
#define SMP 16             // samples per block

__device__ __forceinline__ unsigned umin_u(unsigned a, unsigned b) { return a < b ? a : b; }
__device__ __forceinline__ unsigned umax_u(unsigned a, unsigned b) { return a > b ? a : b; }

// round-to-nearest-even fp32 -> bf16
__device__ __forceinline__ unsigned short bf16_rne(float f) {
  unsigned b = __float_as_uint(f);
  unsigned r = b + 0x7FFFu + ((b >> 16) & 1u);
  return (unsigned short)(r >> 16);
}

// ---------------- ws layout (bytes) ------------------------------------------
// xh 1MB | ch 128K | hb 8K | wb 4MB   -> ~5.2 MB
#define OFF_XH   0u
#define OFF_CH   1048576u
#define OFF_HB   (OFF_CH + 131072u)
#define OFF_WB   (OFF_HB + 8192u)

#define NX4 (N_SMPS * D_IN / 4)            // 131072
#define NC4 (N_FCNS * D_IN / 4)            // 16384
#define NW4 (N_FCNS * D_IN * D_OUT / 4)    // 524288
#define NTOT (NX4 + NC4 + NW4)             // 671744 = 2624 * 256

// ---------------- Kernel 0: bf16 RNE conversion (x, ctrs, W) + norms ---------
// (byte-identical to R15's passing k_prep)
__global__ __launch_bounds__(256) void k_prep(
    const float* __restrict__ x, const float* __restrict__ ctrs,
    const float* __restrict__ wts,
    unsigned short* __restrict__ xh, unsigned short* __restrict__ ch,
    unsigned short* __restrict__ wb, float* __restrict__ hb)
{
  const int gt = blockIdx.x * 256 + threadIdx.x;
  const float* src; unsigned short* dst; int i4;
  if (gt < NX4)            { src = x;    dst = xh; i4 = gt; }
  else if (gt < NX4 + NC4) { src = ctrs; dst = ch; i4 = gt - NX4; }
  else                     { src = wts;  dst = wb; i4 = gt - (NX4 + NC4); }
  float4 v = ((const float4*)src)[i4];
  ushort4 o;
  o.x = bf16_rne(v.x); o.y = bf16_rne(v.y);
  o.z = bf16_rne(v.z); o.w = bf16_rne(v.w);
  ((ushort4*)dst)[i4] = o;

  if (gt < N_FCNS) {   // fp32-exact half-norms from original ctrs
    const float4* cp4 = (const float4*)(ctrs + (size_t)gt * D_IN);
    float a = 0.f;
    #pragma unroll
    for (int q = 0; q < 8; ++q) {
      float4 c = cp4[q];
      a += c.x * c.x + c.y * c.y + c.z * c.z + c.w * c.w;
    }
    hb[gt] = -0.5f * a;
  }
}

// ---------------- Kernel 1: MEGA -- topk + fp64 refine + gather-apply --------
// R15 structure + two stall-killers in phase 1:
//  (a) depth-4 interleaved register prefetch of B-frags (issue-to-use ~288 cyc
//      > ~250 cyc L2 latency; depth-2's 144 cyc was insufficient -- R13/R15)
//  (b) hb staged per-wave in LDS -> per-tile hb read is a short ds_read, not
//      another global load in the vmcnt queue.
// Everything downstream byte-identical to R15 (proven, absmax 1.907e-6).
__global__ __launch_bounds__(256) void k_mega(
    const unsigned short* __restrict__ xh, const unsigned short* __restrict__ ch,
    const float* __restrict__ hb,
    const float* __restrict__ x, const float* __restrict__ ctrs,
    const unsigned short* __restrict__ wb, const float* __restrict__ offs,
    float* __restrict__ y)
{
  // arena: phase1 cand = 4*16*16*4 u32 = 16384 B;
  //        phase4/5 diff = 16*4*33 f32 = 8448 B, part = 16*4*8 f32x4 = 8192 B
  __shared__ __align__(16) char u_mem[16640];
  __shared__ float    s_hb[SPLITS * CPS];                      // 8 KB
  __shared__ unsigned s_pool[SMP][POOL];                       // 3 KB
  __shared__ double   s_pd2[SMP][POOL];                        // 6 KB
  __shared__ int      s_pix[SMP][POOL];                        // 3 KB
  __shared__ int      s_sel[SMP][KNN];                         // 256 B

  unsigned* s_cand = (unsigned*)u_mem;          // [w][row][col][e] flattened
  float*    s_diff = (float*)u_mem;             // [sl][j][33] flattened
  float4*   s_part = (float4*)(u_mem + 8448);   // [sl][j][8] flattened

  const int tid = threadIdx.x;
  const int lane = tid & 63;
  const int w = __builtin_amdgcn_readfirstlane(tid >> 6);  // wave = split
  const int col = lane & 15;
  const int quad = lane >> 4;
  const int sbase = blockIdx.x * SMP;
  const int nbase0 = w * CPS;

  // stage this wave's split hb into LDS (coalesced, once)
  #pragma unroll
  for (int r = 0; r < CPS / 64; ++r)
    s_hb[nbase0 + r * 64 + lane] = hb[nbase0 + r * 64 + lane];

  // ---- Phase 1: MFMA topk (identical key construction to R15) ----
  const bf16x8 ah =
      *(const bf16x8*)(xh + (size_t)(sbase + col) * D_IN + quad * 8);

  unsigned ls[4][4];
  #pragma unroll
  for (int r = 0; r < 4; ++r)
    #pragma unroll
    for (int e = 0; e < 4; ++e) ls[r][e] = 0u;   // real keys always > 0

  const unsigned short* chb =
      ch + (size_t)nbase0 * D_IN + (size_t)col * D_IN + quad * 8;
  #define BLOAD(t) (*(const bf16x8*)(chb + (size_t)(t) * 16 * D_IN))
  #define HLOAD(t) (s_hb[nbase0 + (t) * 16 + col])

  __syncthreads();   // s_hb visible (wave-local anyway; cheap safety)

  bf16x8 bh[4];
  float  hv[4];
  #pragma unroll
  for (int p = 0; p < 4; ++p) { bh[p] = BLOAD(p); hv[p] = HLOAD(p); }

  for (int t = 0; t < TILES; t += 4) {
    #pragma unroll
    for (int p = 0; p < 4; ++p) {
      // process tile t+p from buffer p
      {
        f32x4 acc = {0.f, 0.f, 0.f, 0.f};
        acc = __builtin_amdgcn_mfma_f32_16x16x32_bf16(ah, bh[p], acc, 0, 0, 0);
        const unsigned tc = (unsigned)((t + p) * 16 + col);
        const float hvv = hv[p];
        #pragma unroll
        for (int r = 0; r < 4; ++r) {
          const float uu = acc[r] + hvv;
          unsigned b = __float_as_uint(uu);
          unsigned m = b ^ ((unsigned)((int)b >> 31) | 0x80000000u);
          unsigned key = (m & 0xFFFFFE00u) | tc;
          unsigned t0 = umin_u(ls[r][0], key); ls[r][0] = umax_u(ls[r][0], key);
          unsigned t1 = umin_u(ls[r][1], t0);  ls[r][1] = umax_u(ls[r][1], t0);
          unsigned t2 = umin_u(ls[r][2], t1);  ls[r][2] = umax_u(ls[r][2], t1);
          ls[r][3] = umax_u(ls[r][3], t2);
        }
      }
      // refill buffer p with tile t+4+p (wrap at end; wrapped values unused)
      const int tn = (t + 4 + p) & (TILES - 1);
      bh[p] = BLOAD(tn);
      hv[p] = HLOAD(tn);
    }
  }
  #undef BLOAD
  #undef HLOAD

  #pragma unroll
  for (int r = 0; r < 4; ++r) {
    const int row = quad * 4 + r;
    *(uint4*)&s_cand[(((w * 16) + row) * 16 + col) * 4] =
        make_uint4(ls[r][0], ls[r][1], ls[r][2], ls[r][3]);
  }
  __syncthreads();

  // subset top-6 -> s_pool (same mapping as R15: subset g = wave*2 + half)
  if (tid < 128) {
    const int sl = tid >> 3;
    const int g  = tid & 7;
    const int wv = g >> 1;
    const int chh = (g & 1) * 8;
    unsigned q0 = 0, q1 = 0, q2 = 0, q3 = 0, q4 = 0, q5 = 0;
    #pragma unroll
    for (int c2 = 0; c2 < 8; ++c2) {
      uint4 kv = *(const uint4*)&s_cand[(((wv * 16) + sl) * 16 + chh + c2) * 4];
      unsigned ks[4] = {kv.x, kv.y, kv.z, kv.w};
      #pragma unroll
      for (int e = 0; e < 4; ++e) {
        unsigned key = ks[e];
        unsigned t0 = umin_u(q0, key); q0 = umax_u(q0, key);
        unsigned t1 = umin_u(q1, t0);  q1 = umax_u(q1, t0);
        unsigned t2 = umin_u(q2, t1);  q2 = umax_u(q2, t1);
        unsigned t3 = umin_u(q3, t2);  q3 = umax_u(q3, t2);
        unsigned t4 = umin_u(q4, t3);  q4 = umax_u(q4, t3);
        q5 = umax_u(q5, t4);
      }
    }
    unsigned* op = &s_pool[sl][g * 6];
    op[0] = q0; op[1] = q1; op[2] = q2;
    op[3] = q3; op[4] = q4; op[5] = q5;
  }
  __syncthreads();

  // ---- Phase 2: fp64 exact distances for all 16*48 pool entries ----
  for (int c = tid; c < SMP * POOL; c += 256) {
    const int sl = c / POOL;
    const int p = c - sl * POOL;
    const unsigned key = s_pool[sl][p];
    const int wv = p / 12;
    const int j = wv * CPS + (int)(key & 0x1FFu);
    const float4* xp4 = (const float4*)(x + (size_t)(sbase + sl) * D_IN);
    const float4* cp4 = (const float4*)(ctrs + (size_t)j * D_IN);
    double d2a = 0.0, d2b = 0.0;
    #pragma unroll
    for (int q = 0; q < 8; ++q) {
      float4 cv = cp4[q];
      float4 xv = xp4[q];
      double df0 = (double)xv.x - (double)cv.x;
      double df1 = (double)xv.y - (double)cv.y;
      double df2 = (double)xv.z - (double)cv.z;
      double df3 = (double)xv.w - (double)cv.w;
      d2a = fma(df0, df0, d2a);
      d2b = fma(df1, df1, d2b);
      d2a = fma(df2, df2, d2a);
      d2b = fma(df3, df3, d2b);
    }
    s_pd2[sl][p] = d2a + d2b;
    s_pix[sl][p] = j;
  }
  __syncthreads();

  // ---- Phase 3: per-sample fp64 top-4, np tie-break (proven) ----
  if (tid < SMP) {
    double bd[4]; int b4[4];
    #pragma unroll
    for (int e = 0; e < 4; ++e) { bd[e] = 1e300; b4[e] = 0x7fffffff; }
    for (int m = 0; m < POOL; ++m) {
      const double d2 = s_pd2[tid][m];
      const int j = s_pix[tid][m];
      bool ins = (d2 < bd[3]) || (d2 == bd[3] && j < b4[3]);
      if (ins) {
        bd[3] = d2; b4[3] = j;
        #pragma unroll
        for (int q = 3; q > 0; --q) {
          bool sw = (bd[q] < bd[q - 1]) ||
                    (bd[q] == bd[q - 1] && b4[q] < b4[q - 1]);
          if (sw) {
            double td = bd[q]; bd[q] = bd[q - 1]; bd[q - 1] = td;
            int    tj = b4[q]; b4[q] = b4[q - 1]; b4[q - 1] = tj;
          }
        }
      }
    }
    #pragma unroll
    for (int q = 0; q < 4; ++q) s_sel[tid][q] = b4[q];
  }
  __syncthreads();   // s_cand region dead from here; reuse as diff/part

  // ---- Phase 4: diff staging (overlays dead cand region) ----
  #pragma unroll
  for (int r = 0; r < SMP * KNN * D_IN / 256; ++r) {
    int v = r * 256 + tid;
    int d = v & 31; int p = v >> 5;
    int sl = p >> 2; int j = p & 3;
    int f = s_sel[sl][j];
    s_diff[(sl * KNN + j) * (D_IN + 1) + d] =
        x[(size_t)(sbase + sl) * D_IN + d] - ctrs[(size_t)f * D_IN + d];
  }
  __syncthreads();

  // ---- Phase 5: bf16-W gather-apply, 2 slots/thread (same per-slot math) ----
  #pragma unroll
  for (int r = 0; r < 2; ++r) {
    const int slot = r * 256 + tid;
    const int sl = slot >> 5;
    const int j  = (slot >> 3) & 3;
    const int eq = slot & 7;
    const int f = s_sel[sl][j];
    const uint2* wp = (const uint2*)(wb + (size_t)f * (D_IN * D_OUT));
    float4 acc = ((const float4*)(offs + (size_t)f * D_OUT))[eq];
    #pragma unroll
    for (int d = 0; d < D_IN; ++d) {
      uint2 wv = wp[d * 8 + eq];
      float w0 = __uint_as_float(wv.x << 16);
      float w1 = __uint_as_float(wv.x & 0xFFFF0000u);
      float w2 = __uint_as_float(wv.y << 16);
      float w3 = __uint_as_float(wv.y & 0xFFFF0000u);
      float xc = s_diff[(sl * KNN + j) * (D_IN + 1) + d];
      acc.x = fmaf(xc, w0, acc.x);
      acc.y = fmaf(xc, w1, acc.y);
      acc.z = fmaf(xc, w2, acc.z);
      acc.w = fmaf(xc, w3, acc.w);
    }
    s_part[(sl * KNN + j) * 8 + eq] = acc;
  }
  __syncthreads();

  #pragma unroll
  for (int r = 0; r < 2; ++r) {
    const int slot = r * 256 + tid;
    const int sl = slot >> 5;
    const int j  = (slot >> 3) & 3;
    const int eq = slot & 7;
    if (j == 0) {
      float4 a = s_part[(sl * KNN + 0) * 8 + eq];
      float4 b = s_part[(sl * KNN + 1) * 8 + eq];
      float4 c = s_part[(sl * KNN + 2) * 8 + eq];
      float4 e = s_part[(sl * KNN + 3) * 8 + eq];
      float4 o;
      o.x = (a.x + b.x) + (c.x + e.x);
      o.y = (a.y + b.y) + (c.y + e.y);
      o.z = (a.z + b.z) + (c.z + e.z);
      o.w = (a.w + b.w) + (c.w + e.w);
      ((float4*)(y + (size_t)(sbase + sl) * D_OUT))[eq] = o;
    }
  }
}

// ---------------- launch: 2 dispatches ---------------------------------------
extern "C" void kernel_launch(void* const* d_in, const int* in_sizes, int n_in,
                              void* d_out, int out_size, void* d_ws, size_t ws_size,
                              hipStream_t stream) {
  const float* x    = (const float*)d_in[0];
  const float* ctrs = (const float*)d_in[1];
  const float* wts  = (const float*)d_in[2];
  const float* offs = (const float*)d_in[3];
  float* y = (float*)d_out;

  char* ws = (char*)d_ws;
  unsigned short* xh = (unsigned short*)(ws + OFF_XH);
  unsigned short* ch = (unsigned short*)(ws + OFF_CH);
  float*          hb = (float*)(ws + OFF_HB);
  unsigned short* wb = (unsigned short*)(ws + OFF_WB);

  k_prep<<<NTOT / 256, 256, 0, stream>>>(x, ctrs, wts, xh, ch, wb, hb);
  k_mega<<<N_SMPS / SMP, 256, 0, stream>>>(xh, ch, hb, x, ctrs, wb, offs, y);
}